// Round 11
// baseline (124.293 us; speedup 1.0000x reference)
//
#include <hip/hip_runtime.h>
#include <hip/hip_cooperative_groups.h>
#include <stdint.h>

namespace cg = cooperative_groups;

#define ZD 41
#define YD 1600
#define XD 1408
#define YXD (YD * XD)
#define NKEYS (ZD * YD * XD)    // 92,364,800 linear sites (divisible by 32)
#define ENT_WORDS (NKEYS / 32)  // 2,886,400 u64 entries {hi: bits32, lo: prefix}
#define BN_EPS 1e-3f

typedef unsigned long long u64;

// ---------------- ws layout ----------------
// [0,128)        accum (fallback path only)
// [128,256)      pad (entry[-1] speculative read lands here; always masked out)
// [256, +ENT_WORDS*8)  entry[g]: hi32 = occupancy bits of sites [g*32..g*32+31],
//                      lo32 = # active keys with key < g*32 (merged rank index)
// [+16]          pad (entry[ENT_WORDS] speculative read; masked out)
// [then]         per-block BN partials [nb][32]; then partial2[64][32]

// ============ fused cooperative kernel: build + conv + BN + apply ==========
__global__ void __launch_bounds__(256, 7) fused_all(
    const float4* __restrict__ feats, const int4* __restrict__ coords,
    const float* __restrict__ weight, const float* __restrict__ gamma,
    const float* __restrict__ beta, u64* __restrict__ entry,
    float* __restrict__ partial, float* __restrict__ partial2,
    float* __restrict__ out, int n, int nb, float invN) {
  cg::grid_group grid = cg::this_grid();
  const int tid = threadIdx.x;

  __shared__ float wl[27 * 64];  // [k][c][o] = k*64 + c*16 + o
  __shared__ float swred[4][32];
  __shared__ float red2[8][32];
  __shared__ float redv[32];
  __shared__ float sa[16], sbv[16];

  // ---- Phase A: build merged rank index (flat order; sorted unique keys) ---
  {
    int ia = blockIdx.x * 256 + tid;
    int4 cl = coords[n - 1];  // L2 broadcast
    int glast = ((cl.y * YD + cl.z) * XD + cl.w) >> 5;
    int stride = gridDim.x * 256;
    for (int g = glast + 1 + ia; g < ENT_WORDS; g += stride)
      entry[g] = (u64)(uint32_t)n;  // parallel tail (R4 lesson)
    if (ia < n) {
      int4 c = coords[ia];
      int key = (c.y * YD + c.z) * XD + c.w;
      int g = key >> 5;
      int pkey = __shfl_up(key, 1);
      if ((tid & 63) == 0 && ia > 0) {
        int4 cp = coords[ia - 1];
        pkey = (cp.y * YD + cp.z) * XD + cp.w;
      }
      int pg = (ia > 0) ? (pkey >> 5) : -1;
      if (g != pg) {  // leader: gap-fill left, OR word-mates
        for (int gg = pg + 1; gg < g; ++gg) entry[gg] = (u64)(uint32_t)ia;
        uint32_t bits = 1u << (key & 31);
        int j = ia + 1;
        while (j < n) {
          int4 cj = coords[j];
          int kj = (cj.y * YD + cj.z) * XD + cj.w;
          if ((kj >> 5) != g) break;
          bits |= 1u << (kj & 31);
          ++j;
        }
        entry[g] = ((u64)bits << 32) | (uint32_t)ia;
      }
    }
  }
  __threadfence();
  grid.sync();

  // ---- Phase B: conv, acc stays in registers ----
  for (int t = tid; t < 27 * 64; t += 256) wl[t] = weight[t];
  __syncthreads();

  // Bijective XCD-chunk swizzle: contiguous voxel ranges per XCD (entry-table
  // slice ~2.9MB per XCD L2).
  int B = gridDim.x;
  int q = B >> 3, r = B & 7;
  int xcd = blockIdx.x & 7, off = blockIdx.x >> 3;
  int sbk = (xcd < r ? xcd * (q + 1) : r * (q + 1) + (xcd - r) * q) + off;
  int i = sbk * 256 + tid;

  float acc[16];
#pragma unroll
  for (int o = 0; o < 16; o++) acc[o] = 0.f;

  if (i < n) {
    int4 czyx = coords[i];
    int z = czyx.y, y = czyx.z, x = czyx.w;
    int key = (z * YD + y) * XD + x;

    {  // self contribution (always present, coalesced)
      float4 fs = feats[i];
      const float* wp = &wl[13 * 64];
#pragma unroll
      for (int o = 0; o < 16; o++)
        acc[o] = fs.x * wp[o] + fs.y * wp[o + 16] + fs.z * wp[o + 32] +
                 fs.w * wp[o + 48];
    }

    // 9 windows issued up-front -> 27-bit hit mask
    unsigned mask27 = 0;
#pragma unroll
    for (int dzy = 0; dzy < 9; dzy++) {
      const int dz = dzy / 3 - 1, dy = dzy % 3 - 1;
      bool ok = ((unsigned)(z + dz) < (unsigned)ZD) &&
                ((unsigned)(y + dy) < (unsigned)YD);
      int base = key + dz * YXD + dy * XD - 1;
      int g0 = base >> 5;  // base=-1 -> -1 (pad region, masked)
      u64 e0 = 0, e1 = 0;
      if (ok) {
        e0 = entry[g0];
        e1 = entry[g0 + 1];
      }
      u64 W = (e0 >> 32) | (e1 & 0xFFFFFFFF00000000ull);
      unsigned m3 = (unsigned)(W >> (base & 31)) & 7u;
      mask27 |= m3 << (dzy * 3);
    }
    mask27 &= ~(1u << 13);                   // self done
    if (x == 0) mask27 &= ~0x1249249u;       // dx=-1 bits
    if (x == XD - 1) mask27 &= ~0x4924924u;  // dx=+1 bits

    while (mask27) {  // rare extras (~0.11/voxel), entries L1-hot
      int b = __ffs(mask27) - 1;
      mask27 &= mask27 - 1;
      int dzy = (b * 11) >> 5;
      int rem = b - dzy * 3;
      int dzq = (dzy * 11) >> 5;
      int dyr = dzy - dzq * 3;
      int s = key + (dzq - 1) * YXD + (dyr - 1) * XD + rem - 1;
      int gs = s >> 5;
      u64 e = entry[gs];
      int j = (int)(e & 0xFFFFFFFFull) +
              __popc((uint32_t)(e >> 32) & ((1u << (s & 31)) - 1u));
      float4 f = feats[j];
      const float* wp = &wl[b * 64];
#pragma unroll
      for (int o = 0; o < 16; o++)
        acc[o] += f.x * wp[o] + f.y * wp[o + 16] + f.z * wp[o + 32] +
                  f.w * wp[o + 48];
    }
  }

  // block-level BN partials (inactive threads contribute 0)
  {
    int lane = tid & 63, wv = tid >> 6;
#pragma unroll
    for (int o = 0; o < 16; o++) {
      float s = acc[o], qq = acc[o] * acc[o];
#pragma unroll
      for (int offx = 32; offx; offx >>= 1) {
        s += __shfl_xor(s, offx);
        qq += __shfl_xor(qq, offx);
      }
      if (lane == 0) {
        swred[wv][o] = s;
        swred[wv][16 + o] = qq;
      }
    }
    __syncthreads();
    if (tid < 32) {
      float v = swred[0][tid] + swred[1][tid] + swred[2][tid] + swred[3][tid];
      partial[(size_t)blockIdx.x * 32 + tid] = v;
    }
  }
  __threadfence();
  grid.sync();

  // ---- Phase C: 64 blocks reduce partial[nb][32] -> partial2[64][32] ----
  if (blockIdx.x < 64) {
    int c = tid & 31, s = tid >> 5;
    float v = 0.f;
    for (int rr = blockIdx.x + 64 * s; rr < nb; rr += 512)
      v += partial[(size_t)rr * 32 + c];
    red2[s][c] = v;
    __syncthreads();
    if (tid < 32) {
      float vv = 0.f;
#pragma unroll
      for (int k = 0; k < 8; k++) vv += red2[k][tid];
      partial2[(size_t)blockIdx.x * 32 + tid] = vv;
    }
  }
  __threadfence();
  grid.sync();

  // ---- Phase D: every block reads partial2 (8KB, L2), applies BN+ReLU ----
  {
    int c = tid & 31, s = tid >> 5;
    float v = 0.f;
#pragma unroll
    for (int k = 0; k < 8; k++) v += partial2[(size_t)(s + 8 * k) * 32 + c];
    red2[s][c] = v;
    __syncthreads();
    if (tid < 32) {
      float vv = 0.f;
#pragma unroll
      for (int k = 0; k < 8; k++) vv += red2[k][tid];
      redv[tid] = vv;
    }
    __syncthreads();
    if (tid < 16) {
      float mu = redv[tid] * invN;
      float var = redv[16 + tid] * invN - mu * mu;
      float inv = rsqrtf(var + BN_EPS);
      float a = gamma[tid] * inv;
      sa[tid] = a;
      sbv[tid] = beta[tid] - mu * a;
    }
    __syncthreads();
    if (i < n) {
      float4* o4 = (float4*)(out + (size_t)i * 16);
      float4 t0, t1, t2, t3;
      t0.x = fmaxf(acc[0] * sa[0] + sbv[0], 0.f);
      t0.y = fmaxf(acc[1] * sa[1] + sbv[1], 0.f);
      t0.z = fmaxf(acc[2] * sa[2] + sbv[2], 0.f);
      t0.w = fmaxf(acc[3] * sa[3] + sbv[3], 0.f);
      t1.x = fmaxf(acc[4] * sa[4] + sbv[4], 0.f);
      t1.y = fmaxf(acc[5] * sa[5] + sbv[5], 0.f);
      t1.z = fmaxf(acc[6] * sa[6] + sbv[6], 0.f);
      t1.w = fmaxf(acc[7] * sa[7] + sbv[7], 0.f);
      t2.x = fmaxf(acc[8] * sa[8] + sbv[8], 0.f);
      t2.y = fmaxf(acc[9] * sa[9] + sbv[9], 0.f);
      t2.z = fmaxf(acc[10] * sa[10] + sbv[10], 0.f);
      t2.w = fmaxf(acc[11] * sa[11] + sbv[11], 0.f);
      t3.x = fmaxf(acc[12] * sa[12] + sbv[12], 0.f);
      t3.y = fmaxf(acc[13] * sa[13] + sbv[13], 0.f);
      t3.z = fmaxf(acc[14] * sa[14] + sbv[14], 0.f);
      t3.w = fmaxf(acc[15] * sa[15] + sbv[15], 0.f);
      o4[0] = t0;
      o4[1] = t1;
      o4[2] = t2;
      o4[3] = t3;
    }
  }
}

// ===================== fallback 4-launch path (R8, proven) =================
__global__ void __launch_bounds__(256) build_index(
    const int4* __restrict__ coords, u64* __restrict__ entry, int n) {
  int i = blockIdx.x * blockDim.x + threadIdx.x;
  {
    int4 cl = coords[n - 1];
    int glast = (((cl.y * YD + cl.z) * XD + cl.w)) >> 5;
    int stride = gridDim.x * blockDim.x;
    for (int g = glast + 1 + i; g < ENT_WORDS; g += stride)
      entry[g] = (u64)(uint32_t)n;
  }
  if (i >= n) return;
  int4 c = coords[i];
  int key = (c.y * YD + c.z) * XD + c.w;
  int g = key >> 5;
  int pkey = __shfl_up(key, 1);
  if ((threadIdx.x & 63) == 0 && i > 0) {
    int4 cp = coords[i - 1];
    pkey = (cp.y * YD + cp.z) * XD + cp.w;
  }
  int pg = (i > 0) ? (pkey >> 5) : -1;
  if (g != pg) {
    for (int gg = pg + 1; gg < g; ++gg) entry[gg] = (u64)(uint32_t)i;
    uint32_t bits = 1u << (key & 31);
    int j = i + 1;
    while (j < n) {
      int4 cj = coords[j];
      int kj = (cj.y * YD + cj.z) * XD + cj.w;
      if ((kj >> 5) != g) break;
      bits |= 1u << (kj & 31);
      ++j;
    }
    entry[g] = ((u64)bits << 32) | (uint32_t)i;
  }
}

__global__ void __launch_bounds__(256) subm_conv(
    const float4* __restrict__ feats, const int4* __restrict__ coords,
    const float* __restrict__ weight, const u64* __restrict__ entry,
    float* __restrict__ out, float* __restrict__ partial, int n) {
  __shared__ float wl[27 * 64];
  __shared__ float swred[4][32];
  for (int t = threadIdx.x; t < 27 * 64; t += 256) wl[t] = weight[t];
  __syncthreads();
  int B = gridDim.x;
  int q = B >> 3, r = B & 7;
  int xcd = blockIdx.x & 7, off = blockIdx.x >> 3;
  int sb = (xcd < r ? xcd * (q + 1) : r * (q + 1) + (xcd - r) * q) + off;
  int i = sb * 256 + (int)threadIdx.x;
  float acc[16];
#pragma unroll
  for (int o = 0; o < 16; o++) acc[o] = 0.f;
  if (i < n) {
    int4 czyx = coords[i];
    int z = czyx.y, y = czyx.z, x = czyx.w;
    int key = (z * YD + y) * XD + x;
    {
      float4 fs = feats[i];
      const float* wp = &wl[13 * 64];
#pragma unroll
      for (int o = 0; o < 16; o++)
        acc[o] = fs.x * wp[o] + fs.y * wp[o + 16] + fs.z * wp[o + 32] +
                 fs.w * wp[o + 48];
    }
    unsigned mask27 = 0;
#pragma unroll
    for (int dzy = 0; dzy < 9; dzy++) {
      const int dz = dzy / 3 - 1, dy = dzy % 3 - 1;
      bool ok = ((unsigned)(z + dz) < (unsigned)ZD) &&
                ((unsigned)(y + dy) < (unsigned)YD);
      int base = key + dz * YXD + dy * XD - 1;
      int g0 = base >> 5;
      u64 e0 = 0, e1 = 0;
      if (ok) {
        e0 = entry[g0];
        e1 = entry[g0 + 1];
      }
      u64 W = (e0 >> 32) | (e1 & 0xFFFFFFFF00000000ull);
      unsigned m3 = (unsigned)(W >> (base & 31)) & 7u;
      mask27 |= m3 << (dzy * 3);
    }
    mask27 &= ~(1u << 13);
    if (x == 0) mask27 &= ~0x1249249u;
    if (x == XD - 1) mask27 &= ~0x4924924u;
    while (mask27) {
      int b = __ffs(mask27) - 1;
      mask27 &= mask27 - 1;
      int dzy = (b * 11) >> 5;
      int rem = b - dzy * 3;
      int dzq = (dzy * 11) >> 5;
      int dyr = dzy - dzq * 3;
      int s = key + (dzq - 1) * YXD + (dyr - 1) * XD + rem - 1;
      int gs = s >> 5;
      u64 e = entry[gs];
      int j = (int)(e & 0xFFFFFFFFull) +
              __popc((uint32_t)(e >> 32) & ((1u << (s & 31)) - 1u));
      float4 f = feats[j];
      const float* wp = &wl[b * 64];
#pragma unroll
      for (int o = 0; o < 16; o++)
        acc[o] += f.x * wp[o] + f.y * wp[o + 16] + f.z * wp[o + 32] +
                  f.w * wp[o + 48];
    }
    float4* o4 = (float4*)(out + (size_t)i * 16);
    o4[0] = make_float4(acc[0], acc[1], acc[2], acc[3]);
    o4[1] = make_float4(acc[4], acc[5], acc[6], acc[7]);
    o4[2] = make_float4(acc[8], acc[9], acc[10], acc[11]);
    o4[3] = make_float4(acc[12], acc[13], acc[14], acc[15]);
  }
  int lane = threadIdx.x & 63, wv = threadIdx.x >> 6;
#pragma unroll
  for (int o = 0; o < 16; o++) {
    float s = acc[o], qq = acc[o] * acc[o];
#pragma unroll
    for (int offx = 32; offx; offx >>= 1) {
      s += __shfl_xor(s, offx);
      qq += __shfl_xor(qq, offx);
    }
    if (lane == 0) {
      swred[wv][o] = s;
      swred[wv][16 + o] = qq;
    }
  }
  __syncthreads();
  if (threadIdx.x < 32) {
    float v = swred[0][threadIdx.x] + swred[1][threadIdx.x] +
              swred[2][threadIdx.x] + swred[3][threadIdx.x];
    partial[(size_t)blockIdx.x * 32 + threadIdx.x] = v;
  }
}

__global__ void __launch_bounds__(1024) bn_finalize(
    const float4* __restrict__ partial4, float* __restrict__ accum, int nb) {
  __shared__ float4 s4[1024];
  int t = threadIdx.x;
  int q = t & 7;
  int row0 = t >> 3;
  float4 v = make_float4(0.f, 0.f, 0.f, 0.f);
  for (int b = row0; b < nb; b += 128) {
    float4 p = partial4[(size_t)b * 8 + q];
    v.x += p.x;
    v.y += p.y;
    v.z += p.z;
    v.w += p.w;
  }
  s4[t] = v;
  __syncthreads();
  for (int half = 64; half >= 1; half >>= 1) {
    if (row0 < half) {
      float4 o = s4[t + half * 8];
      v.x += o.x;
      v.y += o.y;
      v.z += o.z;
      v.w += o.w;
      s4[t] = v;
    }
    __syncthreads();
  }
  if (t < 8) ((float4*)accum)[t] = s4[t];
}

__global__ void __launch_bounds__(256) bn_apply(
    float* __restrict__ out, const float* __restrict__ accum,
    const float* __restrict__ gamma, const float* __restrict__ beta, int n4,
    float invN) {
  __shared__ float sa[16], sb[16];
  int t = threadIdx.x;
  if (t < 16) {
    float mu = accum[t] * invN;
    float var = accum[16 + t] * invN - mu * mu;
    float inv = rsqrtf(var + BN_EPS);
    float a = gamma[t] * inv;
    sa[t] = a;
    sb[t] = beta[t] - mu * a;
  }
  __syncthreads();
  int i = blockIdx.x * 256 + t;
  if (i >= n4) return;
  float4* p = (float4*)out;
  float4 v = p[i];
  int c0 = (i & 3) * 4;
  v.x = fmaxf(v.x * sa[c0 + 0] + sb[c0 + 0], 0.f);
  v.y = fmaxf(v.y * sa[c0 + 1] + sb[c0 + 1], 0.f);
  v.z = fmaxf(v.z * sa[c0 + 2] + sb[c0 + 2], 0.f);
  v.w = fmaxf(v.w * sa[c0 + 3] + sb[c0 + 3], 0.f);
  p[i] = v;
}

extern "C" void kernel_launch(void* const* d_in, const int* in_sizes, int n_in,
                              void* d_out, int out_size, void* d_ws,
                              size_t ws_size, hipStream_t stream) {
  const float4* feats = (const float4*)d_in[0];
  const int4* coords = (const int4*)d_in[1];
  const float* weight = (const float*)d_in[2];
  const float* gamma = (const float*)d_in[3];
  const float* beta = (const float*)d_in[4];
  int n = in_sizes[0] / 4;

  float* accum = (float*)d_ws;
  u64* entry = (u64*)((char*)d_ws + 256);
  float* partial = (float*)((char*)d_ws + 256 + (size_t)ENT_WORDS * 8 + 16);
  int nb = (n + 255) / 256;
  float* partial2 = partial + (size_t)nb * 32;
  float* out = (float*)d_out;
  float invN = 1.0f / n;

  // Cooperative path if the whole grid is co-resident (deterministic per
  // device, so graph capture sees the same path every call).
  int maxB = 0, numCU = 0;
  hipOccupancyMaxActiveBlocksPerMultiprocessor(&maxB, fused_all, 256, 0);
  hipDeviceGetAttribute(&numCU, hipDeviceAttributeMultiprocessorCount, 0);

  if ((long)maxB * numCU >= nb) {
    void* args[] = {(void*)&feats, (void*)&coords,  (void*)&weight,
                    (void*)&gamma, (void*)&beta,    (void*)&entry,
                    (void*)&partial, (void*)&partial2, (void*)&out,
                    (void*)&n,     (void*)&nb,      (void*)&invN};
    hipLaunchCooperativeKernel((void*)fused_all, dim3(nb), dim3(256), args, 0,
                               stream);
  } else {
    hipLaunchKernelGGL(build_index, dim3(nb), dim3(256), 0, stream, coords,
                       entry, n);
    hipLaunchKernelGGL(subm_conv, dim3(nb), dim3(256), 0, stream, feats,
                       coords, weight, entry, out, partial, n);
    hipLaunchKernelGGL(bn_finalize, dim3(1), dim3(1024), 0, stream,
                       (const float4*)partial, accum, nb);
    int n4 = n * 4;
    hipLaunchKernelGGL(bn_apply, dim3((n4 + 255) / 256), dim3(256), 0, stream,
                       out, accum, gamma, beta, n4, invN);
  }
}